// Round 5
// baseline (891.872 us; speedup 1.0000x reference)
//
#include <hip/hip_runtime.h>

#define NN 50000
#define EE 800000
#define LL 3
#define HH 4
#define CC 16
#define DD 64
#define GG 512
#define GRAPH_DIM 128

// ---------------------------------------------------------------------------
__global__ void zero_i32(int* p, int n) {
    int i = blockIdx.x * blockDim.x + threadIdx.x;
    if (i < n) p[i] = 0;
}
__global__ void zero_f32(float* p, int n) {
    int i = blockIdx.x * blockDim.x + threadIdx.x;
    if (i < n) p[i] = 0.f;
}

// ---------------------------------------------------------------------------
// CSR build: histogram of dst, exclusive scan, scatter (src, attr) by dst
// ---------------------------------------------------------------------------
__global__ void hist_kernel(const int* __restrict__ dst, int* __restrict__ counts) {
    int e = blockIdx.x * blockDim.x + threadIdx.x;
    if (e < EE) atomicAdd(&counts[dst[e]], 1);
}

__global__ __launch_bounds__(1024) void scan_kernel(const int* __restrict__ counts,
                                                    int* __restrict__ row_ptr,
                                                    int* __restrict__ writepos) {
    __shared__ int wsum[16];
    int t = threadIdx.x, lane = t & 63, wid = t >> 6;
    int base = 0;
    for (int start = 0; start < NN; start += 1024) {
        int idx = start + t;
        int val = (idx < NN) ? counts[idx] : 0;
        int x = val;
        #pragma unroll
        for (int o = 1; o < 64; o <<= 1) {
            int y = __shfl_up(x, o);
            if (lane >= o) x += y;
        }
        if (lane == 63) wsum[wid] = x;
        __syncthreads();
        if (wid == 0) {
            int s = (lane < 16) ? wsum[lane] : 0;
            #pragma unroll
            for (int o = 1; o < 16; o <<= 1) {
                int y = __shfl_up(s, o);
                if (lane >= o) s += y;
            }
            if (lane < 16) wsum[lane] = s;
        }
        __syncthreads();
        int excl = x - val + base + (wid > 0 ? wsum[wid - 1] : 0);
        if (idx < NN) { row_ptr[idx] = excl; writepos[idx] = excl; }
        int total = wsum[15];
        __syncthreads();
        base += total;
    }
    if (t == 0) row_ptr[NN] = base;
}

__global__ void scatter_kernel(const int* __restrict__ ei, const float* __restrict__ attr,
                               int* __restrict__ writepos,
                               int* __restrict__ src_s, float* __restrict__ attr_s) {
    int e = blockIdx.x * blockDim.x + threadIdx.x;
    if (e < EE) {
        int s = ei[e];
        int d = ei[EE + e];
        int p = atomicAdd(&writepos[d], 1);
        src_s[p] = s;
        attr_s[p] = attr[e];
    }
}

// ---------------------------------------------------------------------------
// fused node GEMM: q,k,v,skip = h @ {Wq,Wk,Wv,Ws} + biases
// ---------------------------------------------------------------------------
__global__ __launch_bounds__(256) void node_gemm(
    const float* __restrict__ hx,
    const float* __restrict__ Wq, const float* __restrict__ bq,
    const float* __restrict__ Wk, const float* __restrict__ bk,
    const float* __restrict__ Wv, const float* __restrict__ bv,
    const float* __restrict__ Ws, const float* __restrict__ bs,
    float* __restrict__ q, float* __restrict__ k,
    float* __restrict__ v, float* __restrict__ sk)
{
    __shared__ float xs[32 * 64];
    int t = threadIdx.x;
    int node0 = blockIdx.x * 32;

    const float4* src4 = (const float4*)(hx + (size_t)node0 * 64);
    float4* dst4 = (float4*)xs;
    #pragma unroll
    for (int r = 0; r < 2; ++r) {
        int i4 = t + r * 256;
        int node = node0 + (i4 >> 4);
        float4 val = make_float4(0.f, 0.f, 0.f, 0.f);
        if (node < NN) val = src4[i4];
        dst4[i4] = val;
    }
    __syncthreads();

    int mat = t >> 6, j = t & 63;
    const float* W = (mat == 0) ? Wq : (mat == 1) ? Wk : (mat == 2) ? Wv : Ws;
    const float* B = (mat == 0) ? bq : (mat == 1) ? bk : (mat == 2) ? bv : bs;
    float* O       = (mat == 0) ? q  : (mat == 1) ? k  : (mat == 2) ? v  : sk;

    float wcol[64];
    #pragma unroll
    for (int i = 0; i < 64; ++i) wcol[i] = W[i * 64 + j];
    float bj = B[j];

    for (int n = 0; n < 32; ++n) {
        int node = node0 + n;
        if (node >= NN) break;
        float acc = bj;
        const float4* xr = (const float4*)(xs + n * 64);
        #pragma unroll
        for (int i4 = 0; i4 < 16; ++i4) {
            float4 xv = xr[i4];
            acc = fmaf(xv.x, wcol[4 * i4 + 0], acc);
            acc = fmaf(xv.y, wcol[4 * i4 + 1], acc);
            acc = fmaf(xv.z, wcol[4 * i4 + 2], acc);
            acc = fmaf(xv.w, wcol[4 * i4 + 3], acc);
        }
        O[(size_t)node * 64 + j] = acc;
    }
}

// ---------------------------------------------------------------------------
// fused attention, thread-per-(node,head): 200K independent threads, no
// cross-lane ops, no LDS, no barriers. Each thread owns 16 channels (one
// head) of one dst node; loops the node's CSR edge list with 8 independent
// float4 gathers (k,v head-slice) per edge and next-edge (src,attr)
// prefetch. This is the memory pattern that measured ~11 TB/s effective
// (edge_score, R3) vs ~1.7 TB/s for wave-serial-loop kernels (R2/R3-agg).
//   score = (q.k_head + a * (q.We)_head) / sqrt(C)
//   out16 = (sum ex*v + We*sum ex*a) / (sum ex + 1e-16) + skip
// ---------------------------------------------------------------------------
__global__ __launch_bounds__(256) void node_attn(
    const float* __restrict__ q, const float* __restrict__ k,
    const float* __restrict__ v, const float* __restrict__ sk,
    const float* __restrict__ We,
    const int* __restrict__ row_ptr, const int* __restrict__ src_s,
    const float* __restrict__ attr_s,
    float* __restrict__ out, int do_relu, int do_pool,
    const int* __restrict__ batch,
    float* __restrict__ gsum, float* __restrict__ gcnt)
{
    int t = blockIdx.x * 256 + threadIdx.x;
    if (t >= NN * HH) return;
    int n = t >> 2, h = t & 3;
    int cb = h * 16;
    size_t nb = (size_t)n * 64 + cb;

    const float4* qr = (const float4*)(q + nb);
    const float4* wr = (const float4*)(We + cb);
    float4 q0 = qr[0], q1 = qr[1], q2 = qr[2], q3 = qr[3];
    float4 w0 = wr[0], w1 = wr[1], w2 = wr[2], w3 = wr[3];

    // loop-invariant  qw = q . We  over this head's 16 channels
    float qw = q0.x * w0.x + q0.y * w0.y + q0.z * w0.z + q0.w * w0.w
             + q1.x * w1.x + q1.y * w1.y + q1.z * w1.z + q1.w * w1.w
             + q2.x * w2.x + q2.y * w2.y + q2.z * w2.z + q2.w * w2.w
             + q3.x * w3.x + q3.y * w3.y + q3.z * w3.z + q3.w * w3.w;

    int p0 = row_ptr[n];
    int p1 = row_ptr[n + 1];

    float4 a0 = make_float4(0.f, 0.f, 0.f, 0.f);
    float4 a1 = a0, a2 = a0, a3 = a0;
    float den = 0.f, saw = 0.f;

    int s = (p0 < p1) ? src_s[p0] : 0;
    float a = (p0 < p1) ? attr_s[p0] : 0.f;

    for (int p = p0; p < p1; ++p) {
        // prefetch next edge's (src, attr) while this edge's gathers fly
        int pn = (p + 1 < p1) ? p + 1 : p;
        int s_nx = src_s[pn];
        float a_nx = attr_s[pn];

        const float4* kr = (const float4*)(k + (size_t)s * 64 + cb);
        const float4* vr = (const float4*)(v + (size_t)s * 64 + cb);
        float4 k0 = kr[0], k1 = kr[1], k2 = kr[2], k3 = kr[3];
        float4 v0 = vr[0], v1 = vr[1], v2 = vr[2], v3 = vr[3];

        // 4 partial dot chains for ILP
        float d0 = q0.x * k0.x; d0 = fmaf(q0.y, k0.y, d0);
        d0 = fmaf(q0.z, k0.z, d0); d0 = fmaf(q0.w, k0.w, d0);
        float d1 = q1.x * k1.x; d1 = fmaf(q1.y, k1.y, d1);
        d1 = fmaf(q1.z, k1.z, d1); d1 = fmaf(q1.w, k1.w, d1);
        float d2 = q2.x * k2.x; d2 = fmaf(q2.y, k2.y, d2);
        d2 = fmaf(q2.z, k2.z, d2); d2 = fmaf(q2.w, k2.w, d2);
        float d3 = q3.x * k3.x; d3 = fmaf(q3.y, k3.y, d3);
        d3 = fmaf(q3.z, k3.z, d3); d3 = fmaf(q3.w, k3.w, d3);
        float dot = (d0 + d1) + (d2 + d3);

        float ex = __expf(fmaf(a, qw, dot) * 0.25f);

        a0.x = fmaf(ex, v0.x, a0.x); a0.y = fmaf(ex, v0.y, a0.y);
        a0.z = fmaf(ex, v0.z, a0.z); a0.w = fmaf(ex, v0.w, a0.w);
        a1.x = fmaf(ex, v1.x, a1.x); a1.y = fmaf(ex, v1.y, a1.y);
        a1.z = fmaf(ex, v1.z, a1.z); a1.w = fmaf(ex, v1.w, a1.w);
        a2.x = fmaf(ex, v2.x, a2.x); a2.y = fmaf(ex, v2.y, a2.y);
        a2.z = fmaf(ex, v2.z, a2.z); a2.w = fmaf(ex, v2.w, a2.w);
        a3.x = fmaf(ex, v3.x, a3.x); a3.y = fmaf(ex, v3.y, a3.y);
        a3.z = fmaf(ex, v3.z, a3.z); a3.w = fmaf(ex, v3.w, a3.w);
        den += ex;
        saw = fmaf(ex, a, saw);

        s = s_nx;
        a = a_nx;
    }

    float inv = 1.f / (den + 1e-16f);
    const float4* skr = (const float4*)(sk + nb);
    float4 sk0 = skr[0], sk1 = skr[1], sk2 = skr[2], sk3 = skr[3];

    float4 o0, o1, o2, o3;
    o0.x = fmaf(a0.x + saw * w0.x, inv, sk0.x);
    o0.y = fmaf(a0.y + saw * w0.y, inv, sk0.y);
    o0.z = fmaf(a0.z + saw * w0.z, inv, sk0.z);
    o0.w = fmaf(a0.w + saw * w0.w, inv, sk0.w);
    o1.x = fmaf(a1.x + saw * w1.x, inv, sk1.x);
    o1.y = fmaf(a1.y + saw * w1.y, inv, sk1.y);
    o1.z = fmaf(a1.z + saw * w1.z, inv, sk1.z);
    o1.w = fmaf(a1.w + saw * w1.w, inv, sk1.w);
    o2.x = fmaf(a2.x + saw * w2.x, inv, sk2.x);
    o2.y = fmaf(a2.y + saw * w2.y, inv, sk2.y);
    o2.z = fmaf(a2.z + saw * w2.z, inv, sk2.z);
    o2.w = fmaf(a2.w + saw * w2.w, inv, sk2.w);
    o3.x = fmaf(a3.x + saw * w3.x, inv, sk3.x);
    o3.y = fmaf(a3.y + saw * w3.y, inv, sk3.y);
    o3.z = fmaf(a3.z + saw * w3.z, inv, sk3.z);
    o3.w = fmaf(a3.w + saw * w3.w, inv, sk3.w);

    if (do_relu) {
        o0.x = fmaxf(o0.x, 0.f); o0.y = fmaxf(o0.y, 0.f);
        o0.z = fmaxf(o0.z, 0.f); o0.w = fmaxf(o0.w, 0.f);
        o1.x = fmaxf(o1.x, 0.f); o1.y = fmaxf(o1.y, 0.f);
        o1.z = fmaxf(o1.z, 0.f); o1.w = fmaxf(o1.w, 0.f);
        o2.x = fmaxf(o2.x, 0.f); o2.y = fmaxf(o2.y, 0.f);
        o2.z = fmaxf(o2.z, 0.f); o2.w = fmaxf(o2.w, 0.f);
        o3.x = fmaxf(o3.x, 0.f); o3.y = fmaxf(o3.y, 0.f);
        o3.z = fmaxf(o3.z, 0.f); o3.w = fmaxf(o3.w, 0.f);
    }

    float4* outr = (float4*)(out + nb);
    outr[0] = o0; outr[1] = o1; outr[2] = o2; outr[3] = o3;

    if (do_pool) {
        int b = batch[n];
        float* gs = gsum + (size_t)b * 64 + cb;
        atomicAdd(gs + 0,  o0.x); atomicAdd(gs + 1,  o0.y);
        atomicAdd(gs + 2,  o0.z); atomicAdd(gs + 3,  o0.w);
        atomicAdd(gs + 4,  o1.x); atomicAdd(gs + 5,  o1.y);
        atomicAdd(gs + 6,  o1.z); atomicAdd(gs + 7,  o1.w);
        atomicAdd(gs + 8,  o2.x); atomicAdd(gs + 9,  o2.y);
        atomicAdd(gs + 10, o2.z); atomicAdd(gs + 11, o2.w);
        atomicAdd(gs + 12, o3.x); atomicAdd(gs + 13, o3.y);
        atomicAdd(gs + 14, o3.z); atomicAdd(gs + 15, o3.w);
        if (h == 0) atomicAdd(&gcnt[b], 1.f);
    }
}

// ---------------------------------------------------------------------------
// mean-pool finalize + 3-layer MLP head; one block (128 thr) per graph
// ---------------------------------------------------------------------------
__global__ __launch_bounds__(128) void pool_mlp(
    const float* __restrict__ gsum, const float* __restrict__ gcnt,
    const float* __restrict__ W1, const float* __restrict__ b1,
    const float* __restrict__ W2, const float* __restrict__ b2,
    const float* __restrict__ W3, const float* __restrict__ b3,
    float* __restrict__ out)
{
    __shared__ float g[64];
    __shared__ float h1s[64];
    __shared__ float h2s[16];
    int b = blockIdx.x, t = threadIdx.x;

    if (t < 64) {
        float c = gcnt[b];
        g[t] = gsum[(size_t)b * 64 + t] / fmaxf(c, 1.f);
    }
    __syncthreads();
    if (t < 64) {
        float a = b1[t];
        #pragma unroll
        for (int i = 0; i < 64; ++i) a = fmaf(g[i], W1[i * 64 + t], a);
        h1s[t] = fmaxf(a, 0.f);
    }
    __syncthreads();
    if (t < 16) {
        float a = b2[t];
        #pragma unroll
        for (int i = 0; i < 64; ++i) a = fmaf(h1s[i], W2[i * 16 + t], a);
        h2s[t] = fmaxf(a, 0.f);
    }
    __syncthreads();
    float a = b3[t];
    #pragma unroll
    for (int i = 0; i < 16; ++i) a = fmaf(h2s[i], W3[i * 128 + t], a);
    out[(size_t)b * 128 + t] = a;
}

// ---------------------------------------------------------------------------
extern "C" void kernel_launch(void* const* d_in, const int* in_sizes, int n_in,
                              void* d_out, int out_size, void* d_ws, size_t ws_size,
                              hipStream_t stream) {
    const float* x         = (const float*)d_in[0];
    const float* edge_attr = (const float*)d_in[1];
    const int*   edge_index= (const int*)d_in[2];
    const int*   batch     = (const int*)d_in[3];
    const float* Wq   = (const float*)d_in[4];
    const float* bq   = (const float*)d_in[5];
    const float* Wk   = (const float*)d_in[6];
    const float* bk   = (const float*)d_in[7];
    const float* Wv   = (const float*)d_in[8];
    const float* bv   = (const float*)d_in[9];
    const float* We   = (const float*)d_in[10];
    const float* Wsk  = (const float*)d_in[11];
    const float* bsk  = (const float*)d_in[12];
    const float* W1   = (const float*)d_in[13];
    const float* b1   = (const float*)d_in[14];
    const float* W2   = (const float*)d_in[15];
    const float* b2   = (const float*)d_in[16];
    const float* W3   = (const float*)d_in[17];
    const float* b3   = (const float*)d_in[18];

    float* out        = (float*)d_out;
    float* node_emb   = out;                         // N*64
    float* graph_feat = out + (size_t)NN * 64;       // G*128

    float* wsf    = (float*)d_ws;
    float* q      = wsf;
    float* k      = q    + (size_t)NN * 64;
    float* v      = k    + (size_t)NN * 64;
    float* skp    = v    + (size_t)NN * 64;
    float* h      = skp  + (size_t)NN * 64;
    float* attr_s = h    + (size_t)NN * 64;
    int*   src_s  = (int*)(attr_s + EE);
    int*   row_ptr= src_s + EE;
    int*   wpos   = row_ptr + (NN + 1);
    float* gsum   = (float*)(wpos + NN);
    float* gcnt   = gsum + (size_t)GG * 64;

    // ---- CSR build (dst-sorted edges); reused by all 3 layers ----
    zero_i32<<<(NN + 255) / 256, 256, 0, stream>>>(wpos, NN);
    zero_f32<<<(GG * 64 + GG + 255) / 256, 256, 0, stream>>>(gsum, GG * 64 + GG);
    hist_kernel<<<(EE + 255) / 256, 256, 0, stream>>>(edge_index + EE, wpos);
    scan_kernel<<<1, 1024, 0, stream>>>(wpos, row_ptr, wpos);
    scatter_kernel<<<(EE + 255) / 256, 256, 0, stream>>>(edge_index, edge_attr,
                                                         wpos, src_s, attr_s);

    int gemm_grid = (NN + 31) / 32;
    int attn_grid = (NN * HH + 255) / 256;

    const float* layer_in = x;
    for (int l = 0; l < LL; ++l) {
        const float* Wq_l = Wq + (size_t)l * 64 * 64;
        const float* Wk_l = Wk + (size_t)l * 64 * 64;
        const float* Wv_l = Wv + (size_t)l * 64 * 64;
        const float* Ws_l = Wsk + (size_t)l * 64 * 64;
        const float* bq_l = bq + (size_t)l * 64;
        const float* bk_l = bk + (size_t)l * 64;
        const float* bv_l = bv + (size_t)l * 64;
        const float* bs_l = bsk + (size_t)l * 64;
        const float* We_l = We + (size_t)l * 64;

        node_gemm<<<gemm_grid, 256, 0, stream>>>(layer_in,
            Wq_l, bq_l, Wk_l, bk_l, Wv_l, bv_l, Ws_l, bs_l,
            q, k, v, skp);

        int last = (l == LL - 1);
        float* dst_h = last ? node_emb : h;
        node_attn<<<attn_grid, 256, 0, stream>>>(q, k, v, skp, We_l,
            row_ptr, src_s, attr_s,
            dst_h, /*relu=*/!last, /*pool=*/last,
            batch, gsum, gcnt);

        layer_in = h;
    }

    pool_mlp<<<GG, 128, 0, stream>>>(gsum, gcnt, W1, b1, W2, b2, W3, b3, graph_feat);
}

// Round 6
// 757.620 us; speedup vs baseline: 1.1772x; 1.1772x over previous
//
#include <hip/hip_runtime.h>

#define NN 50000
#define EE 800000
#define LL 3
#define HH 4
#define CC 16
#define DD 64
#define GG 512
#define GRAPH_DIM 128
#define CH 16   // edges per wave in edge_agg (segmented reduction chunk)

// ---------------------------------------------------------------------------
__global__ void zero_i32(int* p, int n) {
    int i = blockIdx.x * blockDim.x + threadIdx.x;
    if (i < n) p[i] = 0;
}
__global__ void zero_f32(float* p, int n) {
    int i = blockIdx.x * blockDim.x + threadIdx.x;
    if (i < n) p[i] = 0.f;
}

// ---------------------------------------------------------------------------
// CSR build: histogram of dst, exclusive scan, scatter (src, dst, attr)
// ---------------------------------------------------------------------------
__global__ void hist_kernel(const int* __restrict__ dst, int* __restrict__ counts) {
    int e = blockIdx.x * blockDim.x + threadIdx.x;
    if (e < EE) atomicAdd(&counts[dst[e]], 1);
}

__global__ __launch_bounds__(1024) void scan_kernel(const int* __restrict__ counts,
                                                    int* __restrict__ row_ptr,
                                                    int* __restrict__ writepos) {
    __shared__ int wsum[16];
    int t = threadIdx.x, lane = t & 63, wid = t >> 6;
    int base = 0;
    for (int start = 0; start < NN; start += 1024) {
        int idx = start + t;
        int val = (idx < NN) ? counts[idx] : 0;
        int x = val;
        #pragma unroll
        for (int o = 1; o < 64; o <<= 1) {
            int y = __shfl_up(x, o);
            if (lane >= o) x += y;
        }
        if (lane == 63) wsum[wid] = x;
        __syncthreads();
        if (wid == 0) {
            int s = (lane < 16) ? wsum[lane] : 0;
            #pragma unroll
            for (int o = 1; o < 16; o <<= 1) {
                int y = __shfl_up(s, o);
                if (lane >= o) s += y;
            }
            if (lane < 16) wsum[lane] = s;
        }
        __syncthreads();
        int excl = x - val + base + (wid > 0 ? wsum[wid - 1] : 0);
        if (idx < NN) { row_ptr[idx] = excl; writepos[idx] = excl; }
        int total = wsum[15];
        __syncthreads();
        base += total;
    }
    if (t == 0) row_ptr[NN] = base;
}

__global__ void scatter_kernel(const int* __restrict__ ei, const float* __restrict__ attr,
                               int* __restrict__ writepos,
                               int* __restrict__ src_s, int* __restrict__ dst_s,
                               float* __restrict__ attr_s) {
    int e = blockIdx.x * blockDim.x + threadIdx.x;
    if (e < EE) {
        int s = ei[e];
        int d = ei[EE + e];
        int p = atomicAdd(&writepos[d], 1);
        src_s[p] = s;
        dst_s[p] = d;
        attr_s[p] = attr[e];
    }
}

// ---------------------------------------------------------------------------
// fused node GEMM: q,k,v,skip = h @ {Wq,Wk,Wv,Ws} + biases
// ---------------------------------------------------------------------------
__global__ __launch_bounds__(256) void node_gemm(
    const float* __restrict__ hx,
    const float* __restrict__ Wq, const float* __restrict__ bq,
    const float* __restrict__ Wk, const float* __restrict__ bk,
    const float* __restrict__ Wv, const float* __restrict__ bv,
    const float* __restrict__ Ws, const float* __restrict__ bs,
    float* __restrict__ q, float* __restrict__ k,
    float* __restrict__ v, float* __restrict__ sk)
{
    __shared__ float xs[32 * 64];
    int t = threadIdx.x;
    int node0 = blockIdx.x * 32;

    const float4* src4 = (const float4*)(hx + (size_t)node0 * 64);
    float4* dst4 = (float4*)xs;
    #pragma unroll
    for (int r = 0; r < 2; ++r) {
        int i4 = t + r * 256;
        int node = node0 + (i4 >> 4);
        float4 val = make_float4(0.f, 0.f, 0.f, 0.f);
        if (node < NN) val = src4[i4];
        dst4[i4] = val;
    }
    __syncthreads();

    int mat = t >> 6, j = t & 63;
    const float* W = (mat == 0) ? Wq : (mat == 1) ? Wk : (mat == 2) ? Wv : Ws;
    const float* B = (mat == 0) ? bq : (mat == 1) ? bk : (mat == 2) ? bv : bs;
    float* O       = (mat == 0) ? q  : (mat == 1) ? k  : (mat == 2) ? v  : sk;

    float wcol[64];
    #pragma unroll
    for (int i = 0; i < 64; ++i) wcol[i] = W[i * 64 + j];
    float bj = B[j];

    for (int n = 0; n < 32; ++n) {
        int node = node0 + n;
        if (node >= NN) break;
        float acc = bj;
        const float4* xr = (const float4*)(xs + n * 64);
        #pragma unroll
        for (int i4 = 0; i4 < 16; ++i4) {
            float4 xv = xr[i4];
            acc = fmaf(xv.x, wcol[4 * i4 + 0], acc);
            acc = fmaf(xv.y, wcol[4 * i4 + 1], acc);
            acc = fmaf(xv.z, wcol[4 * i4 + 2], acc);
            acc = fmaf(xv.w, wcol[4 * i4 + 3], acc);
        }
        O[(size_t)node * 64 + j] = acc;
    }
}

// ---------------------------------------------------------------------------
// phase 1: edge-parallel scores. thread t -> (p = t>>2, h = t&3)
// ex[p*4+h] = exp( q[dst,h,:] . (k[src,h,:] + a*We[h,:]) / 4 )
// proven pattern: 3.2M threads, 4 lanes cover one contiguous 256B row.
// ---------------------------------------------------------------------------
__global__ __launch_bounds__(256) void edge_score(
    const float* __restrict__ q, const float* __restrict__ k,
    const float* __restrict__ We,
    const int* __restrict__ src_s, const int* __restrict__ dst_s,
    const float* __restrict__ attr_s,
    float* __restrict__ ex_s)
{
    int t = blockIdx.x * 256 + threadIdx.x;
    if (t >= EE * HH) return;
    int p = t >> 2, h = t & 3;
    int s = src_s[p];
    int d = dst_s[p];
    float a = attr_s[p];
    const float4* kr = (const float4*)(k + (size_t)s * 64 + h * 16);
    const float4* qr = (const float4*)(q + (size_t)d * 64 + h * 16);
    const float4* wr = (const float4*)(We + h * 16);
    float dot = 0.f;
    #pragma unroll
    for (int i = 0; i < 4; ++i) {
        float4 kv = kr[i];
        float4 qv = qr[i];
        float4 wv = wr[i];
        dot = fmaf(qv.x, fmaf(a, wv.x, kv.x), dot);
        dot = fmaf(qv.y, fmaf(a, wv.y, kv.y), dot);
        dot = fmaf(qv.z, fmaf(a, wv.z, kv.z), dot);
        dot = fmaf(qv.w, fmaf(a, wv.w, kv.w), dot);
    }
    ex_s[t] = __expf(dot * 0.25f);
}

// ---------------------------------------------------------------------------
// phase 2: edge-parallel segmented reduction. One wave per CH-edge CSR
// chunk, lane = channel. All CH v-row gathers issued up-front (independent,
// coalesced 256B rows); register accumulation within a dst segment (edges
// are dst-sorted), coalesced atomicAdd flush at segment boundaries only.
// ---------------------------------------------------------------------------
__global__ __launch_bounds__(256) void edge_agg(
    const float* __restrict__ v,
    const float* __restrict__ ex_s, const float* __restrict__ attr_s,
    const int* __restrict__ src_s, const int* __restrict__ dst_s,
    float* __restrict__ acc, float* __restrict__ den, float* __restrict__ saw)
{
    int wave = (blockIdx.x * 256 + threadIdx.x) >> 6;
    int lane = threadIdx.x & 63;
    int h = lane >> 4;
    int e0 = wave * CH;
    if (e0 >= EE) return;
    int ne = EE - e0; if (ne > CH) ne = CH;

    int srcs[CH]; int ds[CH]; float exs[CH]; float as_[CH];
    #pragma unroll
    for (int i = 0; i < CH; ++i) {
        int e = e0 + ((i < ne) ? i : ne - 1);
        srcs[i] = src_s[e];
        ds[i]   = dst_s[e];
        as_[i]  = attr_s[e];
        exs[i]  = (i < ne) ? ex_s[e * 4 + h] : 0.f;  // padding contributes 0
    }
    float vv[CH];
    #pragma unroll
    for (int i = 0; i < CH; ++i)
        vv[i] = v[(size_t)srcs[i] * 64 + lane];

    int cur = ds[0];
    float av = 0.f, ad = 0.f, asw = 0.f;
    #pragma unroll
    for (int i = 0; i < CH; ++i) {
        int d = ds[i];
        if (d != cur) {   // wave-uniform branch (all lanes same ds sequence)
            atomicAdd(&acc[(size_t)cur * 64 + lane], av);
            if ((lane & 15) == 0) {
                atomicAdd(&den[cur * 4 + h], ad);
                atomicAdd(&saw[cur * 4 + h], asw);
            }
            av = 0.f; ad = 0.f; asw = 0.f; cur = d;
        }
        float e = exs[i];
        av  = fmaf(e, vv[i], av);
        ad += e;
        asw = fmaf(e, as_[i], asw);
    }
    atomicAdd(&acc[(size_t)cur * 64 + lane], av);
    if ((lane & 15) == 0) {
        atomicAdd(&den[cur * 4 + h], ad);
        atomicAdd(&saw[cur * 4 + h], asw);
    }
}

// ---------------------------------------------------------------------------
// phase 3: streaming finalize. thread per (node, channel), no loops.
// out = (acc + saw*We) / (den + 1e-16) + skip ; optional relu + pool.
// ---------------------------------------------------------------------------
__global__ __launch_bounds__(256) void node_finalize(
    const float* __restrict__ acc, const float* __restrict__ den,
    const float* __restrict__ saw, const float* __restrict__ skp,
    const float* __restrict__ We,
    float* __restrict__ out, int do_relu, int do_pool,
    const int* __restrict__ batch,
    float* __restrict__ gsum, float* __restrict__ gcnt)
{
    int t = blockIdx.x * 256 + threadIdx.x;
    if (t >= NN * 64) return;
    int n = t >> 6, c = t & 63;
    int h = c >> 4;
    float d = den[n * 4 + h];
    float s = saw[n * 4 + h];
    float o = (acc[t] + s * We[c]) / (d + 1e-16f) + skp[t];
    if (do_relu) o = fmaxf(o, 0.f);
    out[t] = o;
    if (do_pool) {
        int b = batch[n];
        atomicAdd(&gsum[(size_t)b * 64 + c], o);
        if (c == 0) atomicAdd(&gcnt[b], 1.f);
    }
}

// ---------------------------------------------------------------------------
// mean-pool finalize + 3-layer MLP head; one block (128 thr) per graph
// ---------------------------------------------------------------------------
__global__ __launch_bounds__(128) void pool_mlp(
    const float* __restrict__ gsum, const float* __restrict__ gcnt,
    const float* __restrict__ W1, const float* __restrict__ b1,
    const float* __restrict__ W2, const float* __restrict__ b2,
    const float* __restrict__ W3, const float* __restrict__ b3,
    float* __restrict__ out)
{
    __shared__ float g[64];
    __shared__ float h1s[64];
    __shared__ float h2s[16];
    int b = blockIdx.x, t = threadIdx.x;

    if (t < 64) {
        float c = gcnt[b];
        g[t] = gsum[(size_t)b * 64 + t] / fmaxf(c, 1.f);
    }
    __syncthreads();
    if (t < 64) {
        float a = b1[t];
        #pragma unroll
        for (int i = 0; i < 64; ++i) a = fmaf(g[i], W1[i * 64 + t], a);
        h1s[t] = fmaxf(a, 0.f);
    }
    __syncthreads();
    if (t < 16) {
        float a = b2[t];
        #pragma unroll
        for (int i = 0; i < 64; ++i) a = fmaf(h1s[i], W2[i * 16 + t], a);
        h2s[t] = fmaxf(a, 0.f);
    }
    __syncthreads();
    float a = b3[t];
    #pragma unroll
    for (int i = 0; i < 16; ++i) a = fmaf(h2s[i], W3[i * 128 + t], a);
    out[(size_t)b * 128 + t] = a;
}

// ---------------------------------------------------------------------------
extern "C" void kernel_launch(void* const* d_in, const int* in_sizes, int n_in,
                              void* d_out, int out_size, void* d_ws, size_t ws_size,
                              hipStream_t stream) {
    const float* x         = (const float*)d_in[0];
    const float* edge_attr = (const float*)d_in[1];
    const int*   edge_index= (const int*)d_in[2];
    const int*   batch     = (const int*)d_in[3];
    const float* Wq   = (const float*)d_in[4];
    const float* bq   = (const float*)d_in[5];
    const float* Wk   = (const float*)d_in[6];
    const float* bk   = (const float*)d_in[7];
    const float* Wv   = (const float*)d_in[8];
    const float* bv   = (const float*)d_in[9];
    const float* We   = (const float*)d_in[10];
    const float* Wsk  = (const float*)d_in[11];
    const float* bsk  = (const float*)d_in[12];
    const float* W1   = (const float*)d_in[13];
    const float* b1   = (const float*)d_in[14];
    const float* W2   = (const float*)d_in[15];
    const float* b2   = (const float*)d_in[16];
    const float* W3   = (const float*)d_in[17];
    const float* b3   = (const float*)d_in[18];

    float* out        = (float*)d_out;
    float* node_emb   = out;                         // N*64
    float* graph_feat = out + (size_t)NN * 64;       // G*128

    float* wsf    = (float*)d_ws;
    float* q      = wsf;                             // aliased as acc after edge_score
    float* k      = q    + (size_t)NN * 64;
    float* v      = k    + (size_t)NN * 64;
    float* skp    = v    + (size_t)NN * 64;
    float* h      = skp  + (size_t)NN * 64;
    float* den    = h    + (size_t)NN * 64;          // N*4
    float* saw    = den  + (size_t)NN * 4;           // N*4
    float* attr_s = saw  + (size_t)NN * 4;           // E
    float* ex_s   = attr_s + EE;                     // E*4
    int*   src_s  = (int*)(ex_s + (size_t)EE * HH);  // E
    int*   dst_s  = src_s + EE;                      // E
    int*   row_ptr= dst_s + EE;                      // N+1
    int*   wpos   = row_ptr + (NN + 1);              // N
    float* gsum   = (float*)(wpos + NN);             // G*64
    float* gcnt   = gsum + (size_t)GG * 64;          // G
    float* acc    = q;                               // alias (q dead after edge_score)

    // ---- CSR build (dst-sorted edges); reused by all 3 layers ----
    zero_i32<<<(NN + 255) / 256, 256, 0, stream>>>(wpos, NN);
    zero_f32<<<(GG * 64 + GG + 255) / 256, 256, 0, stream>>>(gsum, GG * 64 + GG);
    hist_kernel<<<(EE + 255) / 256, 256, 0, stream>>>(edge_index + EE, wpos);
    scan_kernel<<<1, 1024, 0, stream>>>(wpos, row_ptr, wpos);
    scatter_kernel<<<(EE + 255) / 256, 256, 0, stream>>>(edge_index, edge_attr,
                                                         wpos, src_s, dst_s, attr_s);

    int gemm_grid  = (NN + 31) / 32;
    int score_grid = (EE * HH + 255) / 256;
    int agg_waves  = (EE + CH - 1) / CH;
    int agg_grid   = (agg_waves + 3) / 4;
    int fin_grid   = (NN * 64 + 255) / 256;

    const float* layer_in = x;
    for (int l = 0; l < LL; ++l) {
        const float* Wq_l = Wq + (size_t)l * 64 * 64;
        const float* Wk_l = Wk + (size_t)l * 64 * 64;
        const float* Wv_l = Wv + (size_t)l * 64 * 64;
        const float* Ws_l = Wsk + (size_t)l * 64 * 64;
        const float* bq_l = bq + (size_t)l * 64;
        const float* bk_l = bk + (size_t)l * 64;
        const float* bv_l = bv + (size_t)l * 64;
        const float* bs_l = bsk + (size_t)l * 64;
        const float* We_l = We + (size_t)l * 64;

        node_gemm<<<gemm_grid, 256, 0, stream>>>(layer_in,
            Wq_l, bq_l, Wk_l, bk_l, Wv_l, bv_l, Ws_l, bs_l,
            q, k, v, skp);

        edge_score<<<score_grid, 256, 0, stream>>>(q, k, We_l,
            src_s, dst_s, attr_s, ex_s);

        // q is dead now; reuse as acc
        zero_f32<<<fin_grid, 256, 0, stream>>>(acc, NN * 64);
        zero_f32<<<(NN * 8 + 255) / 256, 256, 0, stream>>>(den, NN * 8);

        edge_agg<<<agg_grid, 256, 0, stream>>>(v, ex_s, attr_s,
            src_s, dst_s, acc, den, saw);

        int last = (l == LL - 1);
        float* dst_h = last ? node_emb : h;
        node_finalize<<<fin_grid, 256, 0, stream>>>(acc, den, saw, skp, We_l,
            dst_h, /*relu=*/!last, /*pool=*/last, batch, gsum, gcnt);

        layer_in = h;
    }

    pool_mlp<<<GG, 128, 0, stream>>>(gsum, gcnt, W1, b1, W2, b2, W3, b3, graph_feat);
}

// Round 7
// 641.569 us; speedup vs baseline: 1.3901x; 1.1809x over previous
//
#include <hip/hip_runtime.h>

#define NN 50000
#define EE 800000
#define LL 3
#define HH 4
#define CC 16
#define DD 64
#define GG 512
#define GRAPH_DIM 128

// ---------------------------------------------------------------------------
// merged init: wpos[NN] = 0, gsum/gcnt (GG*64+GG floats) = 0
// ---------------------------------------------------------------------------
__global__ void init_ws(int* __restrict__ wpos, float* __restrict__ gsum) {
    int i = blockIdx.x * blockDim.x + threadIdx.x;
    if (i < NN) wpos[i] = 0;
    if (i < GG * 64 + GG) gsum[i] = 0.f;
}

// ---------------------------------------------------------------------------
// CSR build: histogram of dst, exclusive scan, scatter (src, attr) by dst
// ---------------------------------------------------------------------------
__global__ void hist_kernel(const int* __restrict__ dst, int* __restrict__ counts) {
    int e = blockIdx.x * blockDim.x + threadIdx.x;
    if (e < EE) atomicAdd(&counts[dst[e]], 1);
}

__global__ __launch_bounds__(1024) void scan_kernel(const int* __restrict__ counts,
                                                    int* __restrict__ row_ptr,
                                                    int* __restrict__ writepos) {
    __shared__ int wsum[16];
    int t = threadIdx.x, lane = t & 63, wid = t >> 6;
    int base = 0;
    for (int start = 0; start < NN; start += 1024) {
        int idx = start + t;
        int val = (idx < NN) ? counts[idx] : 0;
        int x = val;
        #pragma unroll
        for (int o = 1; o < 64; o <<= 1) {
            int y = __shfl_up(x, o);
            if (lane >= o) x += y;
        }
        if (lane == 63) wsum[wid] = x;
        __syncthreads();
        if (wid == 0) {
            int s = (lane < 16) ? wsum[lane] : 0;
            #pragma unroll
            for (int o = 1; o < 16; o <<= 1) {
                int y = __shfl_up(s, o);
                if (lane >= o) s += y;
            }
            if (lane < 16) wsum[lane] = s;
        }
        __syncthreads();
        int excl = x - val + base + (wid > 0 ? wsum[wid - 1] : 0);
        if (idx < NN) { row_ptr[idx] = excl; writepos[idx] = excl; }
        int total = wsum[15];
        __syncthreads();
        base += total;
    }
    if (t == 0) row_ptr[NN] = base;
}

__global__ void scatter_kernel(const int* __restrict__ ei, const float* __restrict__ attr,
                               int* __restrict__ writepos,
                               int* __restrict__ src_s, float* __restrict__ attr_s) {
    int e = blockIdx.x * blockDim.x + threadIdx.x;
    if (e < EE) {
        int s = ei[e];
        int d = ei[EE + e];
        int p = atomicAdd(&writepos[d], 1);
        src_s[p] = s;
        attr_s[p] = attr[e];
    }
}

// ---------------------------------------------------------------------------
// fused node GEMM: q = h@Wq+bq ; kv[node][0:64] = h@Wk+bk ;
//                  kv[node][64:128] = h@Wv+bv ; sk = h@Ws+bs
// k and v interleaved per node so the attn gathers for one edge land in one
// contiguous 512B region (same L2 set / page).
// ---------------------------------------------------------------------------
__global__ __launch_bounds__(256) void node_gemm(
    const float* __restrict__ hx,
    const float* __restrict__ Wq, const float* __restrict__ bq,
    const float* __restrict__ Wk, const float* __restrict__ bk,
    const float* __restrict__ Wv, const float* __restrict__ bv,
    const float* __restrict__ Ws, const float* __restrict__ bs,
    float* __restrict__ q, float* __restrict__ kv, float* __restrict__ sk)
{
    __shared__ float xs[32 * 64];
    int t = threadIdx.x;
    int node0 = blockIdx.x * 32;

    const float4* src4 = (const float4*)(hx + (size_t)node0 * 64);
    float4* dst4 = (float4*)xs;
    #pragma unroll
    for (int r = 0; r < 2; ++r) {
        int i4 = t + r * 256;
        int node = node0 + (i4 >> 4);
        float4 val = make_float4(0.f, 0.f, 0.f, 0.f);
        if (node < NN) val = src4[i4];
        dst4[i4] = val;
    }
    __syncthreads();

    int mat = t >> 6, j = t & 63;
    const float* W = (mat == 0) ? Wq : (mat == 1) ? Wk : (mat == 2) ? Wv : Ws;
    const float* B = (mat == 0) ? bq : (mat == 1) ? bk : (mat == 2) ? bv : bs;
    float* Obase   = (mat == 0) ? q  : (mat == 1) ? kv : (mat == 2) ? (kv + 64) : sk;
    int    rstride = (mat == 1 || mat == 2) ? 128 : 64;

    float wcol[64];
    #pragma unroll
    for (int i = 0; i < 64; ++i) wcol[i] = W[i * 64 + j];
    float bj = B[j];

    for (int n = 0; n < 32; ++n) {
        int node = node0 + n;
        if (node >= NN) break;
        float acc = bj;
        const float4* xr = (const float4*)(xs + n * 64);
        #pragma unroll
        for (int i4 = 0; i4 < 16; ++i4) {
            float4 xv = xr[i4];
            acc = fmaf(xv.x, wcol[4 * i4 + 0], acc);
            acc = fmaf(xv.y, wcol[4 * i4 + 1], acc);
            acc = fmaf(xv.z, wcol[4 * i4 + 2], acc);
            acc = fmaf(xv.w, wcol[4 * i4 + 3], acc);
        }
        Obase[(size_t)node * rstride + j] = acc;
    }
}

// ---------------------------------------------------------------------------
// fused attention: one wave per dst node, lane = channel. Edge loop unrolled
// x8 with FULL PREDICATION (no scalar remainder): 16 independent row-gathers
// in flight per group (kv rows, 512B contiguous per edge), 8 interleaved
// 4-level shuffle-reduce chains, 8 exps.
//   score = (q.k + a*(q.We))/sqrt(C); out=(sum ex*v + We*sum ex*a)/(sum ex)+skip
// ---------------------------------------------------------------------------
__global__ __launch_bounds__(256) void node_attn(
    const float* __restrict__ q, const float* __restrict__ kv,
    const float* __restrict__ sk, const float* __restrict__ We,
    const int* __restrict__ row_ptr, const int* __restrict__ src_s,
    const float* __restrict__ attr_s,
    float* __restrict__ out, int do_relu, int do_pool,
    const int* __restrict__ batch,
    float* __restrict__ gsum, float* __restrict__ gcnt)
{
    int node = blockIdx.x * 4 + (threadIdx.x >> 6);
    int lane = threadIdx.x & 63;
    if (node >= NN) return;

    size_t nb = (size_t)node * 64;
    float qv = q[nb + lane];
    float we = We[lane];

    float qw = qv * we;
    qw += __shfl_xor(qw, 1);
    qw += __shfl_xor(qw, 2);
    qw += __shfl_xor(qw, 4);
    qw += __shfl_xor(qw, 8);

    int p0 = row_ptr[node];
    int p1 = row_ptr[node + 1];

    float acc = 0.f, den = 0.f, saw = 0.f;

    for (int p = p0; p < p1; p += 8) {
        float kk[8], vv[8], aa[8], rr[8];
        bool mm[8];
        #pragma unroll
        for (int i = 0; i < 8; ++i) {
            int idx = p + i;
            mm[i] = idx < p1;
            if (!mm[i]) idx = p1 - 1;
            int s = src_s[idx];
            aa[i] = attr_s[idx];
            const float* r = kv + (size_t)s * 128 + lane;
            kk[i] = r[0];
            vv[i] = r[64];
        }
        #pragma unroll
        for (int i = 0; i < 8; ++i) rr[i] = qv * kk[i];
        #pragma unroll
        for (int o = 1; o <= 8; o <<= 1) {
            #pragma unroll
            for (int i = 0; i < 8; ++i) rr[i] += __shfl_xor(rr[i], o);
        }
        #pragma unroll
        for (int i = 0; i < 8; ++i) {
            float e = mm[i] ? __expf(fmaf(aa[i], qw, rr[i]) * 0.25f) : 0.f;
            acc = fmaf(e, vv[i], acc);
            den += e;
            saw = fmaf(e, aa[i], saw);
        }
    }

    float o = (acc + saw * we) / (den + 1e-16f) + sk[nb + lane];
    if (do_relu) o = fmaxf(o, 0.f);
    out[nb + lane] = o;

    if (do_pool) {
        int b = batch[node];
        atomicAdd(&gsum[(size_t)b * 64 + lane], o);
        if (lane == 0) atomicAdd(&gcnt[b], 1.f);
    }
}

// ---------------------------------------------------------------------------
// mean-pool finalize + 3-layer MLP head; one block (128 thr) per graph
// ---------------------------------------------------------------------------
__global__ __launch_bounds__(128) void pool_mlp(
    const float* __restrict__ gsum, const float* __restrict__ gcnt,
    const float* __restrict__ W1, const float* __restrict__ b1,
    const float* __restrict__ W2, const float* __restrict__ b2,
    const float* __restrict__ W3, const float* __restrict__ b3,
    float* __restrict__ out)
{
    __shared__ float g[64];
    __shared__ float h1s[64];
    __shared__ float h2s[16];
    int b = blockIdx.x, t = threadIdx.x;

    if (t < 64) {
        float c = gcnt[b];
        g[t] = gsum[(size_t)b * 64 + t] / fmaxf(c, 1.f);
    }
    __syncthreads();
    if (t < 64) {
        float a = b1[t];
        #pragma unroll
        for (int i = 0; i < 64; ++i) a = fmaf(g[i], W1[i * 64 + t], a);
        h1s[t] = fmaxf(a, 0.f);
    }
    __syncthreads();
    if (t < 16) {
        float a = b2[t];
        #pragma unroll
        for (int i = 0; i < 64; ++i) a = fmaf(h1s[i], W2[i * 16 + t], a);
        h2s[t] = fmaxf(a, 0.f);
    }
    __syncthreads();
    float a = b3[t];
    #pragma unroll
    for (int i = 0; i < 16; ++i) a = fmaf(h2s[i], W3[i * 128 + t], a);
    out[(size_t)b * 128 + t] = a;
}

// ---------------------------------------------------------------------------
extern "C" void kernel_launch(void* const* d_in, const int* in_sizes, int n_in,
                              void* d_out, int out_size, void* d_ws, size_t ws_size,
                              hipStream_t stream) {
    const float* x         = (const float*)d_in[0];
    const float* edge_attr = (const float*)d_in[1];
    const int*   edge_index= (const int*)d_in[2];
    const int*   batch     = (const int*)d_in[3];
    const float* Wq   = (const float*)d_in[4];
    const float* bq   = (const float*)d_in[5];
    const float* Wk   = (const float*)d_in[6];
    const float* bk   = (const float*)d_in[7];
    const float* Wv   = (const float*)d_in[8];
    const float* bv   = (const float*)d_in[9];
    const float* We   = (const float*)d_in[10];
    const float* Wsk  = (const float*)d_in[11];
    const float* bsk  = (const float*)d_in[12];
    const float* W1   = (const float*)d_in[13];
    const float* b1   = (const float*)d_in[14];
    const float* W2   = (const float*)d_in[15];
    const float* b2   = (const float*)d_in[16];
    const float* W3   = (const float*)d_in[17];
    const float* b3   = (const float*)d_in[18];

    float* out        = (float*)d_out;
    float* node_emb   = out;                         // N*64
    float* graph_feat = out + (size_t)NN * 64;       // G*128

    float* wsf    = (float*)d_ws;
    float* q      = wsf;
    float* kv     = q    + (size_t)NN * 64;          // N*128 (k|v interleaved)
    float* skp    = kv   + (size_t)NN * 128;
    float* h      = skp  + (size_t)NN * 64;
    float* attr_s = h    + (size_t)NN * 64;          // E
    int*   src_s  = (int*)(attr_s + EE);             // E
    int*   row_ptr= src_s + EE;                      // N+1
    int*   wpos   = row_ptr + (NN + 1);              // N
    float* gsum   = (float*)(wpos + NN);             // G*64 (+G for gcnt)
    float* gcnt   = gsum + (size_t)GG * 64;          // G

    // ---- CSR build (dst-sorted edges); reused by all 3 layers ----
    init_ws<<<(NN + 255) / 256, 256, 0, stream>>>(wpos, gsum);
    hist_kernel<<<(EE + 255) / 256, 256, 0, stream>>>(edge_index + EE, wpos);
    scan_kernel<<<1, 1024, 0, stream>>>(wpos, row_ptr, wpos);
    scatter_kernel<<<(EE + 255) / 256, 256, 0, stream>>>(edge_index, edge_attr,
                                                         wpos, src_s, attr_s);

    int gemm_grid = (NN + 31) / 32;
    int attn_grid = (NN + 3) / 4;

    const float* layer_in = x;
    for (int l = 0; l < LL; ++l) {
        const float* Wq_l = Wq + (size_t)l * 64 * 64;
        const float* Wk_l = Wk + (size_t)l * 64 * 64;
        const float* Wv_l = Wv + (size_t)l * 64 * 64;
        const float* Ws_l = Wsk + (size_t)l * 64 * 64;
        const float* bq_l = bq + (size_t)l * 64;
        const float* bk_l = bk + (size_t)l * 64;
        const float* bv_l = bv + (size_t)l * 64;
        const float* bs_l = bsk + (size_t)l * 64;
        const float* We_l = We + (size_t)l * 64;

        node_gemm<<<gemm_grid, 256, 0, stream>>>(layer_in,
            Wq_l, bq_l, Wk_l, bk_l, Wv_l, bv_l, Ws_l, bs_l,
            q, kv, skp);

        int last = (l == LL - 1);
        float* dst_h = last ? node_emb : h;
        node_attn<<<attn_grid, 256, 0, stream>>>(q, kv, skp, We_l,
            row_ptr, src_s, attr_s,
            dst_h, /*relu=*/!last, /*pool=*/last,
            batch, gsum, gcnt);

        layer_in = h;
    }

    pool_mlp<<<GG, 128, 0, stream>>>(gsum, gcnt, W1, b1, W2, b2, W3, b3, graph_feat);
}